// Round 1
// baseline (855.902 us; speedup 1.0000x reference)
//
#include <hip/hip_runtime.h>
#include <hip/hip_bf16.h>

// FastKANLayer as one bf16 MFMA GEMM:
//   out[b,j] = A[b, i*36+c] @ Wb[i*36+c, j]
//   c<35: A = cubic B-spline basis (4-tap sparse), Wb = spline_weight[i,j,c]
//   c==35: A = silu(clip(x)),                      Wb = base_scale[i,j]
// M=4096, N=1024, K=36864. Tile 128x128x32, 4 waves, split-K=4, atomic epilogue.

#define IN_DIM 1024
#define OUT_DIM 1024
#define NC 35
#define KPI 36
#define KTOT (IN_DIM * KPI)      // 36864
#define MROWS 4096
#define BM 128
#define BN 128
#define BK 32
#define BKP 40                   // padded LDS row in ushorts (80B stride: 2-way bank alias = free)
#define NSPLIT 4
#define KCH (KTOT / NSPLIT)      // 9216
#define NSTEP (KCH / BK)         // 288

typedef __attribute__((ext_vector_type(8))) __bf16 bf16x8;
typedef __attribute__((ext_vector_type(4))) float f32x4;

__device__ __forceinline__ unsigned short f2bf(float f) {
  unsigned int u = __builtin_bit_cast(unsigned int, f);
  u = (u + 0x7FFFu + ((u >> 16) & 1u)) >> 16;   // RNE
  return (unsigned short)u;
}

// ---- prep: Wb[n][k] bf16, k = i*36 + c (c fastest). 75.5 MB in d_ws. ----
__global__ __launch_bounds__(256) void prep_wb(const float* __restrict__ sw,
                                               const float* __restrict__ bs,
                                               unsigned short* __restrict__ wb) {
  int id = blockIdx.x * 256 + threadIdx.x;       // over OUT_DIM*IN_DIM (n,i) pairs
  int i = id & (IN_DIM - 1);
  int n = id >> 10;
  const float* s = sw + (size_t)i * (OUT_DIM * NC) + (size_t)n * NC;
  unsigned short v[KPI];
#pragma unroll
  for (int c = 0; c < NC; ++c) v[c] = f2bf(s[c]);
  v[NC] = f2bf(bs[(size_t)i * OUT_DIM + n]);
  uint2* dst = (uint2*)(wb + (size_t)n * KTOT + (size_t)i * KPI);  // 8B aligned
#pragma unroll
  for (int w = 0; w < 9; ++w) {
    uint2 t;
    t.x = (unsigned)v[4 * w + 0] | ((unsigned)v[4 * w + 1] << 16);
    t.y = (unsigned)v[4 * w + 2] | ((unsigned)v[4 * w + 3] << 16);
    dst[w] = t;
  }
}

template <bool USE_WB>
__global__ __launch_bounds__(256) void kan_gemm(const float* __restrict__ x,
                                                const unsigned short* __restrict__ wb,
                                                const float* __restrict__ sw,
                                                const float* __restrict__ bs,
                                                float* __restrict__ out) {
  __shared__ __align__(16) unsigned short As[BM * BKP];
  __shared__ __align__(16) unsigned short Ws[BN * BKP];

  const int tid = threadIdx.x;
  const int mt = blockIdx.x, nt = blockIdx.y, kc = blockIdx.z;

  // A staging ownership: thread owns row sb, k-halfwindow [klo, klo+16)
  const int sb = tid & 127;
  const int shalf = tid >> 7;
  const int klo = shalf * 16;
  // W staging ownership
  const int wrow = tid >> 1;
  const int whal = tid & 1;
  // wave/fragment ids
  const int lane = tid & 63;
  const int wid = tid >> 6;
  const int wm = (wid & 1) * 64;
  const int wn = (wid >> 1) * 64;
  const int lm = lane & 15;
  const int quad = lane >> 4;
  const int ko = quad * 8;

  f32x4 acc[4][4];
#pragma unroll
  for (int a = 0; a < 4; ++a)
#pragma unroll
    for (int b = 0; b < 4; ++b) acc[a][b] = f32x4{0.f, 0.f, 0.f, 0.f};

  const float* xrow = x + (size_t)(mt * BM + sb) * IN_DIM;

  for (int step = 0; step < NSTEP; ++step) {
    const int kbase = kc * KCH + step * BK;

    // ---- zero my A half-row (same thread scatters into it: no barrier needed between)
    {
      uint4 z = make_uint4(0, 0, 0, 0);
      uint4* az = (uint4*)(&As[sb * BKP + klo]);
      az[0] = z;
      az[1] = z;
    }

    // ---- scatter the 4 B-spline taps + base slot for the 1-2 i's in this K-window
    {
      const int ilo = kbase / KPI;
      const int ihi = (kbase + BK - 1) / KPI;
      for (int ii = ilo; ii <= ihi; ++ii) {
        float xv = xrow[ii];
        float xn = fminf(fmaxf(xv, -0.99f), 0.99f);
        float u = (xn + 1.0f) * 17.0f;     // 1/h = 17
        float sf = floorf(u);
        int s = (int)sf;
        float f = u - sf, g = 1.0f - f;
        float f2 = f * f, g2 = g * g;
        float v0 = g2 * g * (1.f / 6.f);
        float v1 = 0.66666667f - f2 + 0.5f * f2 * f;
        float v2 = 0.66666667f - g2 + 0.5f * g2 * g;
        float v3 = f2 * f * (1.f / 6.f);
        float sig = xn / (1.0f + __expf(-xn));
        const int kb0 = ii * KPI - kbase;  // rel k of (ii, c=0)
#pragma unroll
        for (int t = 0; t < 4; ++t) {
          int c = s - 1 + t;
          float v = (t == 0) ? v0 : (t == 1) ? v1 : (t == 2) ? v2 : v3;
          int kq = kb0 + c;
          if (c >= 0 && c < NC && kq >= klo && kq < klo + 16)
            As[sb * BKP + kq] = f2bf(v);
        }
        int kqb = kb0 + NC;
        if (kqb >= klo && kqb < klo + 16) As[sb * BKP + kqb] = f2bf(sig);
      }
    }

    // ---- stage W tile [BN][BK] (k contiguous per row, bf16)
    if (USE_WB) {
      const unsigned short* src = wb + (size_t)(nt * BN + wrow) * KTOT + kbase + whal * 16;
      uint4 w0 = ((const uint4*)src)[0];
      uint4 w1 = ((const uint4*)src)[1];
      uint4* wd = (uint4*)(&Ws[wrow * BKP + whal * 16]);
      wd[0] = w0;
      wd[1] = w1;
    } else {
      const int j = nt * BN + wrow;
      unsigned int p[8];
#pragma unroll
      for (int q = 0; q < 8; ++q) {
        unsigned int lohi = 0;
#pragma unroll
        for (int h = 0; h < 2; ++h) {
          int k = kbase + whal * 16 + q * 2 + h;
          int i = k / KPI;
          int c = k - i * KPI;
          float v = (c < NC) ? sw[(size_t)i * (OUT_DIM * NC) + (size_t)j * NC + c]
                             : bs[(size_t)i * OUT_DIM + j];
          lohi |= ((unsigned int)f2bf(v)) << (16 * h);
        }
        p[q] = lohi;
      }
      uint4* wd = (uint4*)(&Ws[wrow * BKP + whal * 16]);
      wd[0] = make_uint4(p[0], p[1], p[2], p[3]);
      wd[1] = make_uint4(p[4], p[5], p[6], p[7]);
    }

    __syncthreads();

    // ---- fragments + 16 MFMA
    uint4 af[4], bfr[4];
#pragma unroll
    for (int mi = 0; mi < 4; ++mi)
      af[mi] = *(const uint4*)(&As[(wm + mi * 16 + lm) * BKP + ko]);
#pragma unroll
    for (int ni = 0; ni < 4; ++ni)
      bfr[ni] = *(const uint4*)(&Ws[(wn + ni * 16 + lm) * BKP + ko]);
#pragma unroll
    for (int mi = 0; mi < 4; ++mi)
#pragma unroll
      for (int ni = 0; ni < 4; ++ni)
        acc[mi][ni] = __builtin_amdgcn_mfma_f32_16x16x32_bf16(
            __builtin_bit_cast(bf16x8, af[mi]), __builtin_bit_cast(bf16x8, bfr[ni]),
            acc[mi][ni], 0, 0, 0);

    __syncthreads();
  }

  // ---- epilogue: C/D layout col=lane&15, row=quad*4+reg; split-K partials via atomics
#pragma unroll
  for (int mi = 0; mi < 4; ++mi)
#pragma unroll
    for (int ni = 0; ni < 4; ++ni)
#pragma unroll
      for (int r = 0; r < 4; ++r) {
        int row = mt * BM + wm + mi * 16 + quad * 4 + r;
        int col = nt * BN + wn + ni * 16 + lm;
        atomicAdd(&out[(size_t)row * OUT_DIM + col], acc[mi][ni][r]);
      }
}

extern "C" void kernel_launch(void* const* d_in, const int* in_sizes, int n_in,
                              void* d_out, int out_size, void* d_ws, size_t ws_size,
                              hipStream_t stream) {
  const float* x = (const float*)d_in[0];
  const float* sw = (const float*)d_in[1];
  const float* bs = (const float*)d_in[2];
  float* out = (float*)d_out;

  hipMemsetAsync(d_out, 0, (size_t)MROWS * OUT_DIM * sizeof(float), stream);

  const size_t WB_BYTES = (size_t)OUT_DIM * KTOT * sizeof(unsigned short);  // 75.5 MB
  dim3 grid(MROWS / BM, OUT_DIM / BN, NSPLIT);
  if (ws_size >= WB_BYTES) {
    unsigned short* wbp = (unsigned short*)d_ws;
    prep_wb<<<(IN_DIM * OUT_DIM) / 256, 256, 0, stream>>>(sw, bs, wbp);
    kan_gemm<true><<<grid, 256, 0, stream>>>(x, wbp, sw, bs, out);
  } else {
    kan_gemm<false><<<grid, 256, 0, stream>>>(x, nullptr, sw, bs, out);
  }
}